// Round 12
// baseline (585.747 us; speedup 1.0000x reference)
//
#include <hip/hip_runtime.h>

typedef unsigned short ushort_t;
typedef __attribute__((ext_vector_type(8))) short short8;
typedef __attribute__((ext_vector_type(4))) float f32x4;
typedef __attribute__((ext_vector_type(8))) unsigned short us8;
typedef __attribute__((ext_vector_type(4))) unsigned short us4;

#define SEQ 2048
#define HIDD 2048
#define XLD 3072
#define SCALING 0.08838834764831843f

__device__ __forceinline__ float bf2f(ushort_t u) {
    unsigned int x = ((unsigned int)u) << 16;
    return __builtin_bit_cast(float, x);
}
__device__ __forceinline__ ushort_t f2bf(float f) {
    unsigned int u = __builtin_bit_cast(unsigned int, f);
    u += 0x7fffu + ((u >> 16) & 1u);
    return (ushort_t)(u >> 16);
}

// ------- Transpose + convert: W (K x N) f32 row-major -> Wt rows, bf16 -------
__device__ __forceinline__ void transpose_tile(
    const float* __restrict__ W, ushort_t* __restrict__ Wt,
    int N, int n0, int k0, int dstRow0) {
    __shared__ ushort_t t[64 * 80];
    const int tid = threadIdx.x;
    {
        const int kl = tid >> 4;          // 0..15
        const int nc = (tid & 15) * 4;    // 0..60
        #pragma unroll
        for (int p = 0; p < 4; ++p) {
            int k = kl + p * 16;
            float4 v = *(const float4*)(W + (size_t)(k0 + k) * N + n0 + nc);
            t[(nc + 0) * 80 + k] = f2bf(v.x);
            t[(nc + 1) * 80 + k] = f2bf(v.y);
            t[(nc + 2) * 80 + k] = f2bf(v.z);
            t[(nc + 3) * 80 + k] = f2bf(v.w);
        }
    }
    __syncthreads();
    {
        const int nl = tid >> 3;          // 0..31
        const int kc = (tid & 7) * 8;     // 0..56
        #pragma unroll
        for (int p = 0; p < 2; ++p) {
            int n = nl + p * 32;
            *(us8*)(Wt + (size_t)(dstRow0 + n) * HIDD + k0 + kc) =
                *(const us8*)&t[n * 80 + kc];
        }
    }
}

// All four weight transposes + the hidden f32->bf16 convert in ONE launch.
__global__ __launch_bounds__(256) void transpose_all(
    const float* __restrict__ Wq, const float* __restrict__ Wk,
    const float* __restrict__ Wv, const float* __restrict__ Wo,
    const float* __restrict__ hid,
    ushort_t* __restrict__ Wqkvt, ushort_t* __restrict__ Wot,
    ushort_t* __restrict__ Hb) {
    int bx = blockIdx.x, k0 = blockIdx.y * 64;
    if (bx < 32)       transpose_tile(Wq, Wqkvt, 2048, bx * 64,        k0, bx * 64);
    else if (bx < 40)  transpose_tile(Wk, Wqkvt, 512,  (bx - 32) * 64, k0, 2048 + (bx - 32) * 64);
    else if (bx < 48)  transpose_tile(Wv, Wqkvt, 512,  (bx - 40) * 64, k0, 2560 + (bx - 40) * 64);
    else if (bx < 80)  transpose_tile(Wo, Wot,   2048, (bx - 48) * 64, k0, (bx - 48) * 64);
    else {
        int chunk = (bx - 80) * 32 + blockIdx.y;   // 0..1023, 4096 floats each
        size_t base = (size_t)chunk * 4096 + threadIdx.x * 16;
        #pragma unroll
        for (int p = 0; p < 4; ++p) {
            float4 v = *(const float4*)(hid + base + p * 4);
            us4 o;
            o[0] = f2bf(v.x); o[1] = f2bf(v.y); o[2] = f2bf(v.z); o[3] = f2bf(v.w);
            *(us4*)(Hb + base + p * 4) = o;
        }
    }
}

// ---- Shared GEMM block body: 128x128 tile, BK=64, 4 waves, bf16 partials ----
__device__ __forceinline__ void gemm_body(
    const ushort_t* __restrict__ A, int lda,
    const ushort_t* __restrict__ Bt, int ldb,
    ushort_t* __restrict__ P, int ldc,
    int m0, int n0, int z, const int4 kexts, int zstride,
    ushort_t* lA, ushort_t* lB) {
    const int tid = threadIdx.x;
    const int wave = tid >> 6, lane = tid & 63;
    const int wm = wave >> 1, wn = wave & 1;
    const int quad = lane >> 4, l16 = lane & 15;

    const int ke[4] = {kexts.x, kexts.y, kexts.z, kexts.w};
    int koff = 0;
    for (int zz = 0; zz < 4; ++zz) if (zz < z) koff += ke[zz];
    const int kext = ke[z];

    A  += (size_t)koff;
    Bt += (size_t)koff;
    P  += (size_t)z * (size_t)zstride * ldc;

    const int srow = lane >> 2;
    const int scol = 8 * ((lane & 3) ^ (srow & 3));

    f32x4 acc[4][4] = {};

    const ushort_t* Ab = A  + (size_t)(m0 + wave * 16 + srow) * lda + scol;
    const ushort_t* Bb = Bt + (size_t)(n0 + wave * 16 + srow) * ldb + scol;
    ushort_t* lAw = lA + (wave * 16) * 32;
    ushort_t* lBw = lB + (wave * 16) * 32;

    const int rsw = (quad ^ (l16 & 3)) * 8;

    for (int kk = 0; kk < kext; kk += 64) {
        __syncthreads();
        #pragma unroll
        for (int kh = 0; kh < 2; ++kh) {
            #pragma unroll
            for (int c = 0; c < 2; ++c) {
                __builtin_amdgcn_global_load_lds(
                    (const __attribute__((address_space(1))) unsigned int*)(const void*)
                        (Ab + (size_t)(c * 64) * lda + kk + kh * 32),
                    (__attribute__((address_space(3))) unsigned int*)(void*)
                        (lAw + kh * 128 * 32 + c * 64 * 32), 16, 0, 0);
                __builtin_amdgcn_global_load_lds(
                    (const __attribute__((address_space(1))) unsigned int*)(const void*)
                        (Bb + (size_t)(c * 64) * ldb + kk + kh * 32),
                    (__attribute__((address_space(3))) unsigned int*)(void*)
                        (lBw + kh * 128 * 32 + c * 64 * 32), 16, 0, 0);
            }
        }
        __syncthreads();
        #pragma unroll
        for (int kh = 0; kh < 2; ++kh) {
            short8 af[4], bfr[4];
            #pragma unroll
            for (int mt = 0; mt < 4; ++mt)
                af[mt] = *(const short8*)&lA[kh * 128 * 32 + (wm * 64 + mt * 16 + l16) * 32 + rsw];
            #pragma unroll
            for (int nt = 0; nt < 4; ++nt)
                bfr[nt] = *(const short8*)&lB[kh * 128 * 32 + (wn * 64 + nt * 16 + l16) * 32 + rsw];
            #pragma unroll
            for (int mt = 0; mt < 4; ++mt) {
                #pragma unroll
                for (int nt = 0; nt < 4; ++nt)
                    acc[mt][nt] = __builtin_amdgcn_mfma_f32_16x16x32_bf16(
                        af[mt], bfr[nt], acc[mt][nt], 0, 0, 0);
            }
        }
    }

    #pragma unroll
    for (int mt = 0; mt < 4; ++mt) {
        #pragma unroll
        for (int nt = 0; nt < 4; ++nt) {
            int gm = m0 + wm * 64 + mt * 16 + quad * 4;
            int gn = n0 + wn * 64 + nt * 16 + l16;
            #pragma unroll
            for (int r = 0; r < 4; ++r)
                P[(size_t)(gm + r) * ldc + gn] = f2bf(acc[mt][nt][r]);
        }
    }
}

// -------- QKV GEMM split-K=2 (standalone) ------------------------------------
__global__ __launch_bounds__(256) void gemm_qkv(
    const ushort_t* __restrict__ A, const ushort_t* __restrict__ Bt,
    ushort_t* __restrict__ P) {
    __shared__ ushort_t lA[2 * 128 * 32];
    __shared__ ushort_t lB[2 * 128 * 32];
    gemm_body(A, HIDD, Bt, HIDD, P, XLD,
              blockIdx.y * 128, blockIdx.x * 128, blockIdx.z,
              make_int4(1024, 1024, 0, 0), SEQ, lA, lB);
}

// -------- Fused: Wo GEMM split-K=3 (768 blocks) + dense-weights expander -----
// Every 4th block (bx&3==3) expands compact weights -> dense f32 rows with
// nontemporal stores; the rest run the GEMM. Bands are independent.
__global__ __launch_bounds__(256) void wo_expand(
    const ushort_t* __restrict__ Am, const ushort_t* __restrict__ Wot,
    ushort_t* __restrict__ P,
    const float* __restrict__ cw, float* __restrict__ wts) {
    __shared__ ushort_t lA[2 * 128 * 32];
    __shared__ ushort_t lB[2 * 128 * 32];
    int bx = blockIdx.x;
    if ((bx & 3) != 3) {
        int g = bx - ((bx + 1) >> 2);          // 0..767
        int z = g >> 8, rem = g & 255;
        gemm_body(Am, HIDD, Wot, HIDD, P, HIDD,
                  (rem >> 4) * 128, (rem & 15) * 128, z,
                  make_int4(704, 704, 640, 0), SEQ, lA, lB);
    } else {
        int e = bx >> 2;                       // 0..255
        int wave = threadIdx.x >> 6, lane = threadIdx.x & 63;
        int row0 = e * 128 + wave * 32;
        for (int r = 0; r < 32; ++r) {
            int row = row0 + r;                // row = h*2048 + i
            int i = row & (SEQ - 1);
            int lo = i - 32; if (lo < 0) lo = 0;
            int nsink = lo < 4 ? lo : 4;
            int NJ = nsink + (i - lo + 1);
            float wv = (lane < NJ) ? cw[(size_t)row * 40 + lane] : 0.f;
            float* orow = wts + (size_t)row * SEQ;
            #pragma unroll
            for (int s = 0; s < 8; ++s) {
                f32x4 o;
                #pragma unroll
                for (int t = 0; t < 4; ++t) {
                    int c = s * 256 + lane * 4 + t;
                    bool in = (c < nsink) || (c >= lo && c <= i);
                    int jjc = in ? ((c < nsink) ? c : (nsink + c - lo)) : 0;
                    float val = __shfl(wv, jjc, 64);
                    o[t] = in ? val : 0.f;
                }
                __builtin_nontemporal_store(o, (f32x4*)(orow + s * 256 + lane * 4));
            }
        }
    }
}

// ---- Fused split-K(2) reduce for X: RoPE path (Q/K cols) + V path -----------
#define ROPE_THREADS (SEQ * 20 * 64)
__global__ __launch_bounds__(256) void reduce_x(
    const ushort_t* __restrict__ P, ushort_t* __restrict__ X,
    const float* __restrict__ cosp, const float* __restrict__ sinp) {
    const size_t ZS = (size_t)SEQ * XLD;
    int idx = blockIdx.x * 256 + threadIdx.x;
    if (idx < ROPE_THREADS) {
        int d = idx & 63;
        int rem = idx >> 6;
        int hh = rem % 20;
        int s = rem / 20;
        int cb = (hh < 16) ? hh * 128 : 2048 + (hh - 16) * 128;
        size_t base = (size_t)s * XLD + cb;
        float x1 = bf2f(P[base + d])      + bf2f(P[ZS + base + d]);
        float x2 = bf2f(P[base + d + 64]) + bf2f(P[ZS + base + d + 64]);
        const float* cr = cosp + (size_t)s * 128;
        const float* sr = sinp + (size_t)s * 128;
        X[base + d]      = f2bf(x1 * cr[d]      - x2 * sr[d]);
        X[base + d + 64] = f2bf(x2 * cr[d + 64] + x1 * sr[d + 64]);
    } else {
        int v = (idx - ROPE_THREADS) * 4;   // over SEQ*512
        int c = v & 511;
        int s = v >> 9;
        size_t base = (size_t)s * XLD + 2560 + c;
        us4 a = *(const us4*)(P + base);
        us4 b = *(const us4*)(P + ZS + base);
        us4 o;
        #pragma unroll
        for (int t = 0; t < 4; ++t) o[t] = f2bf(bf2f(a[t]) + bf2f(b[t]));
        *(us4*)(X + base) = o;
    }
}

// ---- Split-K(3) reduce for the final output (bf16 partials -> f32 out) ------
__global__ __launch_bounds__(256) void reduce_out3(
    const ushort_t* __restrict__ P, float* __restrict__ out) {
    const size_t ZS = (size_t)SEQ * HIDD;
    size_t idx = ((size_t)blockIdx.x * 256 + threadIdx.x) * 4;
    us4 a = *(const us4*)(P + idx);
    us4 b = *(const us4*)(P + ZS + idx);
    us4 c = *(const us4*)(P + 2 * ZS + idx);
    float4 o;
    o.x = bf2f(a[0]) + bf2f(b[0]) + bf2f(c[0]);
    o.y = bf2f(a[1]) + bf2f(b[1]) + bf2f(c[1]);
    o.z = bf2f(a[2]) + bf2f(b[2]) + bf2f(c[2]);
    o.w = bf2f(a[3]) + bf2f(b[3]) + bf2f(c[3]);
    *(float4*)(out + idx) = o;
}

// ---------------- Attention: one wave per (head h, query i) ------------------
// Writes compact weights (lane jj -> slot jj, <=37/row) + Am in the
// reference's direct-reshape layout: Am[h*128 + i/16][(i%16)*128 + d] (bf16).
__global__ __launch_bounds__(256) void attn_kernel(
    const ushort_t* __restrict__ X, float* __restrict__ cw,
    ushort_t* __restrict__ Aout) {
    int g = blockIdx.x * 4 + (threadIdx.x >> 6);
    int lane = threadIdx.x & 63;
    int i = g & (SEQ - 1);
    int h = g >> 11;

    const ushort_t* Q = X + (size_t)i * XLD + h * 128;
    unsigned int qv = *(const unsigned int*)(Q + 2 * lane);
    float q0 = bf2f((ushort_t)(qv & 0xffff));
    float q1 = bf2f((ushort_t)(qv >> 16));

    int lo = i - 32; if (lo < 0) lo = 0;
    int nsink = lo < 4 ? lo : 4;
    int NJ = nsink + (i - lo + 1);

    const ushort_t* Kbase = X + 2048 + (h >> 2) * 128;
    const ushort_t* Vbase = X + 2560 + (h >> 2) * 128;

    float m = -1e30f, mysc = -1e30f;
    for (int jj = 0; jj < NJ; ++jj) {
        int j = (jj < nsink) ? jj : (lo + jj - nsink);
        unsigned int kv = *(const unsigned int*)(Kbase + (size_t)j * XLD + 2 * lane);
        float p = q0 * bf2f((ushort_t)(kv & 0xffff)) + q1 * bf2f((ushort_t)(kv >> 16));
        #pragma unroll
        for (int off = 32; off > 0; off >>= 1) p += __shfl_xor(p, off, 64);
        p *= SCALING;
        if (jj == lane) mysc = p;
        m = fmaxf(m, p);
    }
    float e = (lane < NJ) ? expf(mysc - m) : 0.f;
    float l = e;
    #pragma unroll
    for (int off = 32; off > 0; off >>= 1) l += __shfl_xor(l, off, 64);
    float w = e / l;   // lane jj holds weight for slot jj (jj < NJ)

    if (lane < NJ) cw[(size_t)g * 40 + lane] = w;

    float o0 = 0.f, o1 = 0.f;
    for (int jj = 0; jj < NJ; ++jj) {
        int j = (jj < nsink) ? jj : (lo + jj - nsink);
        float pb = __shfl(w, jj, 64);
        unsigned int vv = *(const unsigned int*)(Vbase + (size_t)j * XLD + 2 * lane);
        o0 += pb * bf2f((ushort_t)(vv & 0xffff));
        o1 += pb * bf2f((ushort_t)(vv >> 16));
    }
    int r = h * 128 + (i >> 4);
    int c = (i & 15) * 128 + 2 * lane;
    ushort_t* Ar = Aout + (size_t)r * HIDD + c;
    Ar[0] = f2bf(o0);
    Ar[1] = f2bf(o1);
}

extern "C" void kernel_launch(void* const* d_in, const int* in_sizes, int n_in,
                              void* d_out, int out_size, void* d_ws, size_t ws_size,
                              hipStream_t stream) {
    if (n_in < 7) return;
    const float* hid  = (const float*)d_in[0];
    const float* cosp = (const float*)d_in[1];
    const float* sinp = (const float*)d_in[2];
    const float* Wq   = (const float*)d_in[3];
    const float* Wk   = (const float*)d_in[4];
    const float* Wv   = (const float*)d_in[5];
    const float* Wo   = (const float*)d_in[6];

    float* out = (float*)d_out;                  // attn_output (f32)
    float* wts = out + (size_t)SEQ * HIDD;       // attn_weights (f32)

    // workspace layout
    ushort_t* Hb    = (ushort_t*)d_ws;                    // 2048x2048 bf16
    ushort_t* Wqkvt = Hb    + (size_t)2048 * 2048;        // 3072x2048
    ushort_t* Wot   = Wqkvt + (size_t)3072 * 2048;        // 2048x2048
    ushort_t* X     = Wot   + (size_t)2048 * 2048;        // 2048x3072
    ushort_t* Am    = X     + (size_t)SEQ * XLD;          // 2048x2048
    ushort_t* Pqkv  = Am    + (size_t)SEQ * HIDD;         // 2 x 2048x3072
    ushort_t* Pout  = Pqkv  + 2 * (size_t)SEQ * XLD;      // 3 x 2048x2048
    float*    cw    = (float*)(Pout + 3 * (size_t)SEQ * HIDD); // 32768 x 40 f32
    size_t need = ((char*)(cw + (size_t)32768 * 40)) - (char*)d_ws;
    if (ws_size < need) return;

    dim3 blk(256);
    // all weight transposes + hidden convert in one launch
    transpose_all<<<dim3(112, 32), blk, 0, stream>>>(
        Wq, Wk, Wv, Wo, hid, Wqkvt, Wot, Hb);

    // fused QKV projection, split-K=2 (1024+1024) -> bf16 partials
    gemm_qkv<<<dim3(24, 16, 2), blk, 0, stream>>>(Hb, Wqkvt, Pqkv);
    reduce_x<<<(ROPE_THREADS + SEQ * 512 / 4) / 256, blk, 0, stream>>>(
        Pqkv, X, cosp, sinp);

    // attention: compact weights + Am
    attn_kernel<<<(SEQ * 16) / 4, blk, 0, stream>>>(X, cw, Am);

    // fused: Wo GEMM split-K=3 (704+704+640) + dense-weights expansion
    wo_expand<<<dim3(1024), blk, 0, stream>>>(Am, Wot, Pout, cw, wts);
    reduce_out3<<<(SEQ * HIDD) / (256 * 4), blk, 0, stream>>>(Pout, out);
}